// Round 2
// baseline (162.470 us; speedup 1.0000x reference)
//
#include <hip/hip_runtime.h>
#include <math.h>

// Problem constants (match reference)
#define BB 4096
#define LL 128
#define DD 64

// Strategy: no mu staging in LDS (was 34.8 KB -> capped occupancy at 4 blocks/CU).
// Phase 2 gathers mu in column layout purely for the q accumulation (registers);
// phase 3 re-gathers the same rows (L1/L2-hot) in row layout for the score dots.
// LDS ~3.4 KB -> occupancy is wave-limited: 8 blocks/CU at <=64 VGPRs.
__global__ __launch_bounds__(256, 8) void softmax_attn_cos_kernel(
    const int* __restrict__ ids_a, const int* __restrict__ mask_a,
    const int* __restrict__ ids_b, const int* __restrict__ mask_b,
    const float* __restrict__ mu_table, const float* __restrict__ feat_table,
    float* __restrict__ out)
{
    __shared__ int   s_ids[LL];
    __shared__ float s_m[LL];
    __shared__ float s_q[DD];
    __shared__ float s_part[4][DD];
    __shared__ float s_sc[LL];
    __shared__ float s_mean[2][DD];
    __shared__ float s_sum;

    const int tid  = threadIdx.x;
    const int d    = tid & 63;
    const int lsub = tid >> 6;      // 0..3 (wave id)
    const int b    = blockIdx.x;

    for (int side = 0; side < 2; ++side) {
        const int* ids = side ? ids_b  : ids_a;
        const int* msk = side ? mask_b : mask_a;

        // ---- phase 1: load ids + mask (one load per thread) ----
        if (tid < LL) {
            s_ids[tid] = ids[b * LL + tid];
        } else {
            s_m[tid - LL] = (float)msk[b * LL + (tid - LL)];
        }
        __syncthreads();

        // ---- phase 2: gather mu (column layout, coalesced 256B/row/wave),
        //      masked column-sum for q in registers ----
        float qacc = 0.f;
        #pragma unroll 8
        for (int j = 0; j < 32; ++j) {
            const int l = lsub * 32 + j;
            qacc = fmaf(mu_table[(size_t)s_ids[l] * DD + d], s_m[l], qacc);
        }
        s_part[lsub][d] = qacc;
        __syncthreads();

        // ---- q = masked mean (wave 0) ----
        if (tid < 64) {
            float mv = s_m[tid] + s_m[tid + 64];
            #pragma unroll
            for (int off = 32; off; off >>= 1) mv += __shfl_xor(mv, off, 64);
            const float denom = fmaxf(mv, 1.0f);
            s_q[d] = (s_part[0][d] + s_part[1][d] + s_part[2][d] + s_part[3][d]) / denom;
        }
        __syncthreads();

        // ---- phase 3: scores[l] = mu[l] . q — re-gather mu rows (L1/L2-hot),
        //      2 threads per row, 8 float4 loads each, pair-combine via shuffle ----
        {
            const int l = tid >> 1;
            const int h = tid & 1;
            const float4* rowp = (const float4*)(mu_table + (size_t)s_ids[l] * DD + h * 32);
            const float4* qp   = (const float4*)(&s_q[h * 32]);
            float acc = 0.f;
            #pragma unroll
            for (int k = 0; k < 8; ++k) {
                const float4 v  = rowp[k];
                const float4 qq = qp[k];
                acc += v.x * qq.x + v.y * qq.y + v.z * qq.z + v.w * qq.w;
            }
            acc += __shfl_xor(acc, 1, 64);   // lanes 2j/2j+1 hold the two halves
            if (h == 0) s_sc[l] = (s_m[l] > 0.5f) ? acc : -1e9f;
        }
        __syncthreads();

        // ---- phase 4: softmax over 128 scores (wave 0 butterfly) ----
        if (tid < 64) {
            const float s1 = s_sc[tid], s2 = s_sc[tid + 64];
            float mx = fmaxf(s1, s2);
            #pragma unroll
            for (int off = 32; off; off >>= 1) mx = fmaxf(mx, __shfl_xor(mx, off, 64));
            const float e1 = expf(s1 - mx), e2 = expf(s2 - mx);
            s_sc[tid] = e1; s_sc[tid + 64] = e2;
            float sm = e1 + e2;
            #pragma unroll
            for (int off = 32; off; off >>= 1) sm += __shfl_xor(sm, off, 64);
            if (tid == 0) s_sum = sm;
        }
        __syncthreads();

        // ---- phase 5: out[d] = sum_l attn[l] * feat[id[l]][d] (coalesced gather) ----
        float oacc = 0.f;
        #pragma unroll 8
        for (int j = 0; j < 32; ++j) {
            const int l = lsub * 32 + j;
            oacc = fmaf(feat_table[(size_t)s_ids[l] * DD + d], s_sc[l], oacc);
        }
        s_part[lsub][d] = oacc;
        __syncthreads();
        if (tid < 64) {
            s_mean[side][d] =
                (s_part[0][d] + s_part[1][d] + s_part[2][d] + s_part[3][d]) / s_sum;
        }
        __syncthreads();
    }

    // ---- cosine similarity * 5 (wave 0 butterfly) ----
    if (tid < 64) {
        const float a = s_mean[0][tid], c = s_mean[1][tid];
        float dt = a * c, na = a * a, nb = c * c;
        #pragma unroll
        for (int off = 32; off; off >>= 1) {
            dt += __shfl_xor(dt, off, 64);
            na += __shfl_xor(na, off, 64);
            nb += __shfl_xor(nb, off, 64);
        }
        if (tid == 0) {
            const float denom = fmaxf(sqrtf(na), 1e-8f) * fmaxf(sqrtf(nb), 1e-8f);
            out[b] = 5.0f * dt / denom;
        }
    }
}

extern "C" void kernel_launch(void* const* d_in, const int* in_sizes, int n_in,
                              void* d_out, int out_size, void* d_ws, size_t ws_size,
                              hipStream_t stream) {
    const int*   ids_a  = (const int*)d_in[0];
    const int*   mask_a = (const int*)d_in[1];
    const int*   ids_b  = (const int*)d_in[2];
    const int*   mask_b = (const int*)d_in[3];
    const float* mu     = (const float*)d_in[4];
    const float* feat   = (const float*)d_in[5];
    float* out = (float*)d_out;

    softmax_attn_cos_kernel<<<BB, 256, 0, stream>>>(
        ids_a, mask_a, ids_b, mask_b, mu, feat, out);
}